// Round 18
// baseline (110.988 us; speedup 1.0000x reference)
//
#include <hip/hip_runtime.h>

constexpr int Bb = 8;
constexpr int Nn = 2048;
constexpr int Cc = 64;
constexpr int CAPS = 192;

typedef __attribute__((ext_vector_type(4))) float f32x4;
typedef __attribute__((ext_vector_type(16))) float f32x16;
typedef __attribute__((ext_vector_type(8))) short bf16x8;
typedef __attribute__((ext_vector_type(4))) unsigned u32x4;

__device__ inline unsigned short f2bf(float f){
  unsigned u = __builtin_bit_cast(unsigned, f);
  unsigned r = (u + 0x7FFFu + ((u>>16)&1u)) >> 16;
  return (unsigned short)r;
}
__device__ inline float bf2f(unsigned short h){
  unsigned u = ((unsigned)h)<<16; return __builtin_bit_cast(float,u);
}
__device__ inline unsigned pk2(float a, float b){
  return (unsigned)f2bf(a) | ((unsigned)f2bf(b)<<16);
}

typedef __attribute__((address_space(1))) unsigned GU32;
typedef __attribute__((address_space(3))) unsigned LU32;
__device__ inline void load_lds16(const void* g, void* l){
  __builtin_amdgcn_global_load_lds((const GU32*)g, (LU32*)l, 16, 0, 0);
}

// counted-vmcnt pipeline fences (T4): per-wave wait for own loads, then barrier
#define PIPE_FENCE_N(N) do{ \
    asm volatile("s_waitcnt vmcnt(" #N ")" ::: "memory"); \
    __builtin_amdgcn_sched_barrier(0); \
    __builtin_amdgcn_s_barrier(); \
    __builtin_amdgcn_sched_barrier(0); }while(0)

// frag-major layouts: 16B chunk index -> element offset (in shorts)
__device__ inline size_t qk_chunk(int b, int s, int q, int l){
  return ((((size_t)b*64 + s)*4 + q)*64 + l)*8;
}
__device__ inline size_t xz_chunk(int b, int mq, int cb, int l){
  return ((((size_t)b*128 + mq)*2 + cb)*64 + l)*8;
}

#define MFMA32(a,b,c) __builtin_amdgcn_mfma_f32_32x32x16_bf16(a,b,c,0,0,0)

// ===== mega: prep | extract | WvT | zero-P =====
__global__ __launch_bounds__(256) void mega_k(
    const float* __restrict__ x, const float* __restrict__ A,
    const float* __restrict__ Wq, const float* __restrict__ Wk,
    const float* __restrict__ Tw, const float* __restrict__ Wv,
    unsigned short* __restrict__ Qhi, unsigned short* __restrict__ Qlo,
    unsigned short* __restrict__ Khi, unsigned short* __restrict__ Klo,
    float* __restrict__ xt, float* __restrict__ Xp,
    float* __restrict__ r_, float* __restrict__ diagA, int* __restrict__ cnt,
    int* __restrict__ idx, float* __restrict__ val,
    float* __restrict__ WvT, unsigned short* __restrict__ xf,
    float* __restrict__ P){
  __shared__ __attribute__((aligned(16))) char smem[65792];
  int blk = blockIdx.x; int t = threadIdx.x;

  if(blk < 256){
    float* wql = (float*)smem;
    float* wkl = wql + 4096;
    float* twl = wkl + 4096;
    float (*xr)[64] = (float(*)[64])(twl + 4096);
    float* xsl = (float*)(xr + 64);
    #pragma unroll
    for(int i=0;i<4;i++){
      *(f32x4*)&wql[i*1024+t*4] = *(const f32x4*)&Wq[i*1024+t*4];
      *(f32x4*)&wkl[i*1024+t*4] = *(const f32x4*)&Wk[i*1024+t*4];
      *(f32x4*)&twl[i*1024+t*4] = *(const f32x4*)&Tw[i*1024+t*4];
    }
    if(t<64) xsl[t]=0.f;
    long long row0 = (long long)blk*64;
    int r = t>>4, q = t&15, c0 = q*4;
    #pragma unroll
    for(int i=0;i<4;i++){
      int row = i*16 + r;
      *(f32x4*)&xr[row][c0] = *(const f32x4*)&x[(row0+row)*Cc + c0];
    }
    __syncthreads();
    f32x4 aq[4], ak[4], at4[4];
    #pragma unroll
    for(int g=0;g<4;g++){ aq[g]=(f32x4){0,0,0,0}; ak[g]=(f32x4){0,0,0,0}; at4[g]=(f32x4){0,0,0,0}; }
    for(int kk=0;kk<64;kk++){
      f32x4 wq4 = *(const f32x4*)&wql[kk*64+c0];
      f32x4 wk4 = *(const f32x4*)&wkl[kk*64+c0];
      f32x4 wt4 = *(const f32x4*)&twl[kk*64+c0];
      #pragma unroll
      for(int g=0;g<4;g++){
        float xv = xr[g*16+r][kk];
        aq[g] += xv*wq4; ak[g] += xv*wk4; at4[g] += xv*wt4;
      }
    }
    float xsp[4] = {0.f,0.f,0.f,0.f};
    int q2 = c0>>4, hb = (c0>>3)&1, cs = c0&7;
    #pragma unroll
    for(int g=0;g<4;g++){
      #pragma unroll
      for(int d=0;d<4;d++) xsp[d] += xr[g*16+r][c0+d];
      long long rg = row0 + g*16 + r;
      unsigned long long hq=0,lq=0,hk=0,lk=0;
      #pragma unroll
      for(int d=0;d<4;d++){
        float v = aq[g][d];
        unsigned short h = f2bf(v); unsigned short lo2 = f2bf(v - bf2f(h));
        hq |= (unsigned long long)h << (16*d); lq |= (unsigned long long)lo2 << (16*d);
        v = ak[g][d];
        h = f2bf(v); lo2 = f2bf(v - bf2f(h));
        hk |= (unsigned long long)h << (16*d); lk |= (unsigned long long)lo2 << (16*d);
      }
      int b2 = (int)(rg>>11); int s2 = ((int)rg>>5)&63;
      int l2 = ((int)rg&31) + 32*hb;
      size_t off = qk_chunk(b2, s2, q2, l2) + cs;
      *(unsigned long long*)&Qhi[off] = hq;
      *(unsigned long long*)&Qlo[off] = lq;
      *(unsigned long long*)&Khi[off] = hk;
      *(unsigned long long*)&Klo[off] = lk;
      *(f32x4*)&xt[rg*Cc + c0] = at4[g];
    }
    __syncthreads();
    #pragma unroll
    for(int d=0;d<4;d++) atomicAdd(&xsl[c0+d], xsp[d]);
    __syncthreads();
    if(t<64) Xp[blk*64+t] = xsl[t];
    {
      int b2 = blk>>5; int m0 = (blk&31)*64;
      #pragma unroll
      for(int i=0;i<2;i++){
        int k2 = i*256 + t; int mg2 = k2>>6; int c = k2&63;
        int mloc = mg2*8;
        unsigned u0 = pk2(xr[mloc+0][c], xr[mloc+1][c]);
        unsigned u1 = pk2(xr[mloc+2][c], xr[mloc+3][c]);
        unsigned u2 = pk2(xr[mloc+4][c], xr[mloc+5][c]);
        unsigned u3 = pk2(xr[mloc+6][c], xr[mloc+7][c]);
        u32x4 uu = {u0,u1,u2,u3};
        int mq = (m0 + mloc)>>4; int cb = c>>5; int l2 = (c&31) + 32*(mg2&1);
        *(u32x4*)(xf + xz_chunk(b2, mq, cb, l2)) = uu;
      }
    }
  } else if(blk < 768){
    int n = (blk-256)*4 + (t>>6); int l = t&63;
    const float* row = A + (size_t)n*Nn;
    float mn = 1e30f;
    for(int j=l;j<Nn;j+=64) mn = fminf(mn, row[j]);
    #pragma unroll
    for(int off=32;off>=1;off>>=1) mn = fminf(mn, __shfl_xor(mn,off));
    float thr = mn*1.3f;
    int bse=0;
    for(int j0=0;j0<Nn;j0+=64){
      float v = row[j0+l];
      bool f = v>thr;
      unsigned long long m = __ballot(f);
      int pos = __popcll(m & ((1ull<<l)-1ull));
      if(f && bse+pos<CAPS){ idx[n*CAPS+bse+pos]=j0+l; val[n*CAPS+bse+pos]=v-mn; }
      bse += __popcll(m);
    }
    if(l==0){ r_[n]=mn; diagA[n]=row[n]; cnt[n] = bse<CAPS? bse : CAPS; }
  } else if(blk < 800){
    float (*tile)[65] = (float(*)[65])smem;
    int n0 = (blk-768)*64;
    for(int i=0;i<16;i++){
      int cc = i*4 + (t>>6); int nn2 = t&63;
      tile[cc][nn2] = Wv[(size_t)cc*Nn + n0 + nn2];
    }
    __syncthreads();
    for(int i=0;i<16;i++){
      int nn2 = i*4 + (t>>6); int cc = t&63;
      WvT[(size_t)(n0+nn2)*Cc + cc] = tile[cc][nn2];
    }
  } else {
    // zero P: 64 blocks x 64 KB
    char* dst = (char*)P + (size_t)(blk-800)*65536;
    uint4 zz = {0,0,0,0};
    #pragma unroll
    for(int i=0;i<16;i++) *(uint4*)(dst + ((size_t)i*256 + t)*16) = zz;
  }
}

// ===== zpass: Zp[jq][b][m]; 8 j-octants; 3-buffer counted-vmcnt pipeline =====
__global__ __launch_bounds__(256,4) void zpass_k(
    const unsigned short* __restrict__ Qhi, const unsigned short* __restrict__ Qlo,
    const unsigned short* __restrict__ Khi, const unsigned short* __restrict__ Klo,
    float* __restrict__ Zp){
  __shared__ uint4 stg[3][512];   // 24 KB
  int id = blockIdx.x;
  int b = id&7; int mg = (id>>3)&15; int jq = id>>7;   // 8 x 16 x 8 = 1024 blocks
  int t = threadIdx.x, w = t>>6, l = t&63;
  int mt = mg*4 + w;
  bf16x8 Kh[4], Kl4[4];
  #pragma unroll
  for(int q=0;q<4;q++){
    Kh[q]  = *(const bf16x8*)(Khi + qk_chunk(b, mt, q, l));
    Kl4[q] = *(const bf16x8*)(Klo + qk_chunk(b, mt, q, l));
  }
#define ZISSUE(S, BI) { \
    char* wb = (char*)&stg[BI][0] + ((t>>6)<<10); \
    load_lds16(Qhi + qk_chunk(b,(S),0,0) + t*8, wb); \
    load_lds16(Qlo + qk_chunk(b,(S),0,0) + t*8, wb + 4096); }
  ZISSUE(jq*8,   0);
  ZISSUE(jq*8+1, 1);
  float zacc = 0.f;
  #pragma unroll
  for(int it=0; it<8; it++){
    const int bi = it%3;
    if(it==7) PIPE_FENCE_N(0); else PIPE_FENCE_N(2);
    f32x16 sa, sb;
    #pragma unroll
    for(int r=0;r<16;r++){ sa[r]=0.f; sb[r]=0.f; }
    #pragma unroll
    for(int q=0;q<4;q++){
      bf16x8 Qh4 = *(const bf16x8*)&stg[bi][q*64 + l];
      bf16x8 Ql4 = *(const bf16x8*)&stg[bi][256 + q*64 + l];
      sa = MFMA32(Qh4, Kh[q],  sa);
      sb = MFMA32(Ql4, Kh[q],  sb);
      sb = MFMA32(Qh4, Kl4[q], sb);
    }
    float p = 0.f;
    #pragma unroll
    for(int r=0;r<16;r++) p += __expf(sa[r]+sb[r]);
    zacc += p;
    if(it+2<8) ZISSUE(jq*8+it+2, (it+2)%3);
  }
#undef ZISSUE
  zacc += __shfl_down(zacc, 32);
  if(l<32) Zp[((size_t)(jq*8 + b))*Nn + mt*32 + l] = zacc;
}

// ===== fused: P[b,j,c] += per-m-quarter contributions via atomicAdd (no psum) =====
__global__ __launch_bounds__(256,4) void fused_k(
    const unsigned short* __restrict__ Qhi, const unsigned short* __restrict__ Qlo,
    const unsigned short* __restrict__ Khi, const unsigned short* __restrict__ Klo,
    const unsigned short* __restrict__ xf, const float* __restrict__ Zp,
    float* __restrict__ P){
  __shared__ uint4 stg[3][768];  // 36 KB
  __shared__ float lniz[512];
  int id = blockIdx.x;
  int b = id&7; int jb = (id>>3)&15; int mo = id>>7;   // 8 x 16 x 4 = 512 blocks
  int t = threadIdx.x, w = t>>6, l = t&63, lr = l&31, hh = l>>5;
  int js = jb*4 + w;
  #pragma unroll
  for(int i=0;i<2;i++){
    int m = mo*512 + i*256 + t;
    float z = 0.f;
    #pragma unroll
    for(int p=0;p<8;p++) z += Zp[((size_t)(p*8 + b))*Nn + m];
    lniz[i*256+t] = -__logf(z);
  }
  bf16x8 Qh4[4], Ql4[4];
  #pragma unroll
  for(int q=0;q<4;q++){
    Qh4[q] = *(const bf16x8*)(Qhi + qk_chunk(b, js, q, l));
    Ql4[q] = *(const bf16x8*)(Qlo + qk_chunk(b, js, q, l));
  }
  __syncthreads();   // lniz visible to all waves
#define FISSUE(S, BI) { \
    char* wb = (char*)&stg[BI][0] + ((t>>6)<<10); \
    load_lds16(Khi + qk_chunk(b,(S),0,0) + t*8, wb); \
    load_lds16(Klo + qk_chunk(b,(S),0,0) + t*8, wb + 4096); \
    load_lds16(xf + xz_chunk(b,2*(S),0,0) + t*8, wb + 8192); }
  FISSUE(mo*16,   0);
  FISSUE(mo*16+1, 1);
  f32x16 pa0, pa1;
  #pragma unroll
  for(int r=0;r<16;r++){ pa0[r]=0.f; pa1[r]=0.f; }
  #pragma unroll
  for(int it=0; it<16; it++){
    const int bi = it%3;
    if(it==15) PIPE_FENCE_N(0); else PIPE_FENCE_N(3);
    f32x16 sa, sb;
    #pragma unroll
    for(int r=0;r<16;r++){ sa[r]=0.f; sb[r]=0.f; }
    #pragma unroll
    for(int q=0;q<4;q++){
      bf16x8 Kh4 = *(const bf16x8*)&stg[bi][q*64 + l];
      bf16x8 Kl4 = *(const bf16x8*)&stg[bi][256 + q*64 + l];
      sa = MFMA32(Kh4, Qh4[q], sa);
      sb = MFMA32(Kl4, Qh4[q], sb);
      sb = MFMA32(Kh4, Ql4[q], sb);
    }
    bf16x8 b00 = *(const bf16x8*)&stg[bi][512 + l];
    bf16x8 b10 = *(const bf16x8*)&stg[bi][512 + 64 + l];
    bf16x8 b01 = *(const bf16x8*)&stg[bi][512 + 128 + l];
    bf16x8 b11 = *(const bf16x8*)&stg[bi][512 + 192 + l];
    float e[16];
    #pragma unroll
    for(int r=0;r<16;r++){
      int mrow = (r&3) + 8*(r>>2) + 4*hh;
      e[r] = __expf(sa[r] + sb[r] + lniz[it*32 + mrow]);
    }
    unsigned wd0,wd1,wd2,wd3,wd4,wd5,wd6,wd7;
    {
      unsigned x0 = pk2(e[0],  e[1]);
      unsigned x1 = pk2(e[2],  e[3]);
      unsigned y0 = pk2(e[4],  e[5]);
      unsigned y1 = pk2(e[6],  e[7]);
      asm("v_permlane32_swap_b32 %0, %1" : "+v"(x0), "+v"(y0));
      asm("v_permlane32_swap_b32 %0, %1" : "+v"(x1), "+v"(y1));
      wd0=x0; wd1=x1; wd2=y0; wd3=y1;
      unsigned x2 = pk2(e[8],  e[9]);
      unsigned x3 = pk2(e[10], e[11]);
      unsigned y2 = pk2(e[12], e[13]);
      unsigned y3 = pk2(e[14], e[15]);
      asm("v_permlane32_swap_b32 %0, %1" : "+v"(x2), "+v"(y2));
      asm("v_permlane32_swap_b32 %0, %1" : "+v"(x3), "+v"(y3));
      wd4=x2; wd5=x3; wd6=y2; wd7=y3;
    }
    u32x4 u1 = {wd0,wd1,wd2,wd3};
    u32x4 u2 = {wd4,wd5,wd6,wd7};
    bf16x8 f1 = __builtin_bit_cast(bf16x8, u1);
    bf16x8 f2 = __builtin_bit_cast(bf16x8, u2);
    pa0 = MFMA32(f1, b00, pa0);
    pa0 = MFMA32(f2, b01, pa0);
    pa1 = MFMA32(f1, b10, pa1);
    pa1 = MFMA32(f2, b11, pa1);
    if(it+2<16) FISSUE(mo*16+it+2, (it+2)%3);
  }
#undef FISSUE
  float* Pb = P + ((size_t)b*Nn + js*32)*Cc;
  #pragma unroll
  for(int r=0;r<16;r++){
    int jr = (r&3) + 8*(r>>2) + 4*hh;
    atomicAdd(&Pb[(size_t)jr*Cc + lr],      pa0[r]);
    atomicAdd(&Pb[(size_t)jr*Cc + 32 + lr], pa1[r]);
  }
}

// ---------------- final: dy_diag + elementwise combine (single P gather) ----------------
__global__ __launch_bounds__(256) void final_k(const float* __restrict__ x,
    const float* __restrict__ xt, const float* __restrict__ P,
    const float* __restrict__ WvT, const float* __restrict__ Xp,
    const float* __restrict__ r_, const float* __restrict__ diagA,
    const int* __restrict__ cnt, const int* __restrict__ idx,
    const float* __restrict__ val, const float* __restrict__ tb,
    const float* __restrict__ alp, const float* __restrict__ bet,
    float* __restrict__ out){
  int t=threadIdx.x; int l=t&63;
  int bn = blockIdx.x*4 + (t>>6);
  int b = bn>>11, n = bn&2047;
  float wv = WvT[n*Cc+l];
  float xs = 0.f;
  const float* xpb = Xp + (size_t)b*32*Cc;
  #pragma unroll 8
  for(int p=0;p<32;p++) xs += xpb[p*Cc + l];
  float tacc = r_[n]*xs;
  int cn = cnt[n];
  const float* Pb = P + (size_t)b*Nn*Cc;
  const int* ix = idx + n*CAPS;
  const float* vl = val + n*CAPS;
  for(int k=0;k<cn;k++)
    tacc += vl[k] * Pb[(size_t)ix[k]*Cc + l];
  float d = wv*tacc;
  #pragma unroll
  for(int off=32;off>=1;off>>=1) d += __shfl_xor(d,off);
  size_t g = (size_t)bn*Cc + l;
  float o = alp[0]*diagA[n]*x[g] + bet[0]*(d*xt[g] + tb[l]);
  out[g] = fmaxf(o,0.f);
}

extern "C" void kernel_launch(void* const* d_in, const int* in_sizes, int n_in,
                              void* d_out, int out_size, void* d_ws, size_t ws_size,
                              hipStream_t stream){
  const float* x  = (const float*)d_in[0];
  const float* A  = (const float*)d_in[1];
  const float* Wq = (const float*)d_in[2];
  const float* Wk = (const float*)d_in[3];
  const float* Wv = (const float*)d_in[4];
  const float* Tw = (const float*)d_in[5];
  const float* tb = (const float*)d_in[6];
  const float* alp= (const float*)d_in[7];
  const float* bet= (const float*)d_in[8];
  float* out = (float*)d_out;

  char* base = (char*)d_ws; size_t off=0;
  auto al=[&](size_t sz)->void*{ void* q = base+off; off=(off+sz+255)&~(size_t)255; return q; };
  unsigned short* Qhi=(unsigned short*)al((size_t)Bb*Nn*Cc*2);
  unsigned short* Qlo=(unsigned short*)al((size_t)Bb*Nn*Cc*2);
  unsigned short* Khi=(unsigned short*)al((size_t)Bb*Nn*Cc*2);
  unsigned short* Klo=(unsigned short*)al((size_t)Bb*Nn*Cc*2);
  float* xt  =(float*)al((size_t)Bb*Nn*Cc*4);
  float* P   =(float*)al((size_t)Bb*Nn*Cc*4);    // zeroed by mega_k, accumulated by fused_k
  float* Zp  =(float*)al((size_t)8*Bb*Nn*4);
  float* Xp  =(float*)al((size_t)256*Cc*4);
  float* WvT =(float*)al((size_t)Nn*Cc*4);
  float* r_  =(float*)al((size_t)Nn*4);
  float* dgA =(float*)al((size_t)Nn*4);
  int*   cnt =(int*)al((size_t)Nn*4);
  int*   idx =(int*)al((size_t)Nn*CAPS*4);
  float* val =(float*)al((size_t)Nn*CAPS*4);
  unsigned short* xf=(unsigned short*)al((size_t)Bb*Cc*Nn*2);
  (void)ws_size; (void)n_in; (void)in_sizes; (void)out_size;

  mega_k<<<864, 256, 0, stream>>>(x, A, Wq, Wk, Tw, Wv,
      Qhi, Qlo, Khi, Klo, xt, Xp, r_, dgA, cnt, idx, val, WvT, xf, P);
  zpass_k<<<1024, 256, 0, stream>>>(Qhi,Qlo,Khi,Klo,Zp);
  fused_k<<<512, 256, 0, stream>>>(Qhi,Qlo,Khi,Klo,xf,Zp,P);
  final_k<<<Bb*Nn/4, 256, 0, stream>>>(x,xt,P,WvT,Xp,r_,dgA,cnt,idx,val,tb,alp,bet,out);
}

// Round 19
// 107.316 us; speedup vs baseline: 1.0342x; 1.0342x over previous
//
#include <hip/hip_runtime.h>

constexpr int Bb = 8;
constexpr int Nn = 2048;
constexpr int Cc = 64;
constexpr int CAPS = 192;

typedef __attribute__((ext_vector_type(4))) float f32x4;
typedef __attribute__((ext_vector_type(16))) float f32x16;
typedef __attribute__((ext_vector_type(8))) short bf16x8;
typedef __attribute__((ext_vector_type(4))) unsigned u32x4;

__device__ inline unsigned short f2bf(float f){
  unsigned u = __builtin_bit_cast(unsigned, f);
  unsigned r = (u + 0x7FFFu + ((u>>16)&1u)) >> 16;
  return (unsigned short)r;
}
__device__ inline float bf2f(unsigned short h){
  unsigned u = ((unsigned)h)<<16; return __builtin_bit_cast(float,u);
}
__device__ inline unsigned pk2(float a, float b){
  return (unsigned)f2bf(a) | ((unsigned)f2bf(b)<<16);
}

typedef __attribute__((address_space(1))) unsigned GU32;
typedef __attribute__((address_space(3))) unsigned LU32;
__device__ inline void load_lds16(const void* g, void* l){
  __builtin_amdgcn_global_load_lds((const GU32*)g, (LU32*)l, 16, 0, 0);
}

// counted-vmcnt pipeline fences (T4): per-wave wait for own loads, then barrier
#define PIPE_FENCE_N(N) do{ \
    asm volatile("s_waitcnt vmcnt(" #N ")" ::: "memory"); \
    __builtin_amdgcn_sched_barrier(0); \
    __builtin_amdgcn_s_barrier(); \
    __builtin_amdgcn_sched_barrier(0); }while(0)

// frag-major layouts: 16B chunk index -> element offset (in shorts)
__device__ inline size_t qk_chunk(int b, int s, int q, int l){
  return ((((size_t)b*64 + s)*4 + q)*64 + l)*8;
}
__device__ inline size_t xz_chunk(int b, int mq, int cb, int l){
  return ((((size_t)b*128 + mq)*2 + cb)*64 + l)*8;
}

#define MFMA32(a,b,c) __builtin_amdgcn_mfma_f32_32x32x16_bf16(a,b,c,0,0,0)

// ===== mega: prep(QK hi/lo frag-major + xt + xf frag-major + xsum partials) | extract | WvT =====
__global__ __launch_bounds__(256) void mega_k(
    const float* __restrict__ x, const float* __restrict__ A,
    const float* __restrict__ Wq, const float* __restrict__ Wk,
    const float* __restrict__ Tw, const float* __restrict__ Wv,
    unsigned short* __restrict__ Qhi, unsigned short* __restrict__ Qlo,
    unsigned short* __restrict__ Khi, unsigned short* __restrict__ Klo,
    float* __restrict__ xt, float* __restrict__ Xp,
    float* __restrict__ r_, float* __restrict__ diagA, int* __restrict__ cnt,
    int* __restrict__ idx, float* __restrict__ val,
    float* __restrict__ WvT, unsigned short* __restrict__ xf){
  __shared__ __attribute__((aligned(16))) char smem[65792];
  int blk = blockIdx.x; int t = threadIdx.x;

  if(blk < 256){
    float* wql = (float*)smem;
    float* wkl = wql + 4096;
    float* twl = wkl + 4096;
    float (*xr)[64] = (float(*)[64])(twl + 4096);
    float* xsl = (float*)(xr + 64);
    #pragma unroll
    for(int i=0;i<4;i++){
      *(f32x4*)&wql[i*1024+t*4] = *(const f32x4*)&Wq[i*1024+t*4];
      *(f32x4*)&wkl[i*1024+t*4] = *(const f32x4*)&Wk[i*1024+t*4];
      *(f32x4*)&twl[i*1024+t*4] = *(const f32x4*)&Tw[i*1024+t*4];
    }
    if(t<64) xsl[t]=0.f;
    long long row0 = (long long)blk*64;
    int r = t>>4, q = t&15, c0 = q*4;
    #pragma unroll
    for(int i=0;i<4;i++){
      int row = i*16 + r;
      *(f32x4*)&xr[row][c0] = *(const f32x4*)&x[(row0+row)*Cc + c0];
    }
    __syncthreads();
    f32x4 aq[4], ak[4], at4[4];
    #pragma unroll
    for(int g=0;g<4;g++){ aq[g]=(f32x4){0,0,0,0}; ak[g]=(f32x4){0,0,0,0}; at4[g]=(f32x4){0,0,0,0}; }
    for(int kk=0;kk<64;kk++){
      f32x4 wq4 = *(const f32x4*)&wql[kk*64+c0];
      f32x4 wk4 = *(const f32x4*)&wkl[kk*64+c0];
      f32x4 wt4 = *(const f32x4*)&twl[kk*64+c0];
      #pragma unroll
      for(int g=0;g<4;g++){
        float xv = xr[g*16+r][kk];
        aq[g] += xv*wq4; ak[g] += xv*wk4; at4[g] += xv*wt4;
      }
    }
    float xsp[4] = {0.f,0.f,0.f,0.f};
    int q2 = c0>>4, hb = (c0>>3)&1, cs = c0&7;
    #pragma unroll
    for(int g=0;g<4;g++){
      #pragma unroll
      for(int d=0;d<4;d++) xsp[d] += xr[g*16+r][c0+d];
      long long rg = row0 + g*16 + r;
      unsigned long long hq=0,lq=0,hk=0,lk=0;
      #pragma unroll
      for(int d=0;d<4;d++){
        float v = aq[g][d];
        unsigned short h = f2bf(v); unsigned short lo2 = f2bf(v - bf2f(h));
        hq |= (unsigned long long)h << (16*d); lq |= (unsigned long long)lo2 << (16*d);
        v = ak[g][d];
        h = f2bf(v); lo2 = f2bf(v - bf2f(h));
        hk |= (unsigned long long)h << (16*d); lk |= (unsigned long long)lo2 << (16*d);
      }
      int b2 = (int)(rg>>11); int s2 = ((int)rg>>5)&63;
      int l2 = ((int)rg&31) + 32*hb;
      size_t off = qk_chunk(b2, s2, q2, l2) + cs;
      *(unsigned long long*)&Qhi[off] = hq;
      *(unsigned long long*)&Qlo[off] = lq;
      *(unsigned long long*)&Khi[off] = hk;
      *(unsigned long long*)&Klo[off] = lk;
      *(f32x4*)&xt[rg*Cc + c0] = at4[g];
    }
    __syncthreads();
    #pragma unroll
    for(int d=0;d<4;d++) atomicAdd(&xsl[c0+d], xsp[d]);
    __syncthreads();
    if(t<64) Xp[blk*64+t] = xsl[t];
    {
      int b2 = blk>>5; int m0 = (blk&31)*64;
      #pragma unroll
      for(int i=0;i<2;i++){
        int k2 = i*256 + t; int mg2 = k2>>6; int c = k2&63;
        int mloc = mg2*8;
        unsigned u0 = pk2(xr[mloc+0][c], xr[mloc+1][c]);
        unsigned u1 = pk2(xr[mloc+2][c], xr[mloc+3][c]);
        unsigned u2 = pk2(xr[mloc+4][c], xr[mloc+5][c]);
        unsigned u3 = pk2(xr[mloc+6][c], xr[mloc+7][c]);
        u32x4 uu = {u0,u1,u2,u3};
        int mq = (m0 + mloc)>>4; int cb = c>>5; int l2 = (c&31) + 32*(mg2&1);
        *(u32x4*)(xf + xz_chunk(b2, mq, cb, l2)) = uu;
      }
    }
  } else if(blk < 768){
    int n = (blk-256)*4 + (t>>6); int l = t&63;
    const float* row = A + (size_t)n*Nn;
    float mn = 1e30f;
    for(int j=l;j<Nn;j+=64) mn = fminf(mn, row[j]);
    #pragma unroll
    for(int off=32;off>=1;off>>=1) mn = fminf(mn, __shfl_xor(mn,off));
    float thr = mn*1.3f;
    int bse=0;
    for(int j0=0;j0<Nn;j0+=64){
      float v = row[j0+l];
      bool f = v>thr;
      unsigned long long m = __ballot(f);
      int pos = __popcll(m & ((1ull<<l)-1ull));
      if(f && bse+pos<CAPS){ idx[n*CAPS+bse+pos]=j0+l; val[n*CAPS+bse+pos]=v-mn; }
      bse += __popcll(m);
    }
    if(l==0){ r_[n]=mn; diagA[n]=row[n]; cnt[n] = bse<CAPS? bse : CAPS; }
  } else {
    float (*tile)[65] = (float(*)[65])smem;
    int n0 = (blk-768)*64;
    for(int i=0;i<16;i++){
      int cc = i*4 + (t>>6); int nn2 = t&63;
      tile[cc][nn2] = Wv[(size_t)cc*Nn + n0 + nn2];
    }
    __syncthreads();
    for(int i=0;i<16;i++){
      int nn2 = i*4 + (t>>6); int cc = t&63;
      WvT[(size_t)(n0+nn2)*Cc + cc] = tile[cc][nn2];
    }
  }
}

// ===== zpass: Zp[jq][b][m]; 8 j-octants; 3-buffer counted-vmcnt pipeline; 4 blocks/CU =====
__global__ __launch_bounds__(256,4) void zpass_k(
    const unsigned short* __restrict__ Qhi, const unsigned short* __restrict__ Qlo,
    const unsigned short* __restrict__ Khi, const unsigned short* __restrict__ Klo,
    float* __restrict__ Zp){
  __shared__ uint4 stg[3][512];   // 24 KB
  int id = blockIdx.x;
  int b = id&7; int mg = (id>>3)&15; int jq = id>>7;   // 8 x 16 x 8 = 1024 blocks
  int t = threadIdx.x, w = t>>6, l = t&63;
  int mt = mg*4 + w;
  bf16x8 Kh[4], Kl4[4];
  #pragma unroll
  for(int q=0;q<4;q++){
    Kh[q]  = *(const bf16x8*)(Khi + qk_chunk(b, mt, q, l));
    Kl4[q] = *(const bf16x8*)(Klo + qk_chunk(b, mt, q, l));
  }
#define ZISSUE(S, BI) { \
    char* wb = (char*)&stg[BI][0] + ((t>>6)<<10); \
    load_lds16(Qhi + qk_chunk(b,(S),0,0) + t*8, wb); \
    load_lds16(Qlo + qk_chunk(b,(S),0,0) + t*8, wb + 4096); }
  ZISSUE(jq*8,   0);
  ZISSUE(jq*8+1, 1);
  float zacc = 0.f;
  #pragma unroll
  for(int it=0; it<8; it++){
    const int bi = it%3;
    if(it==7) PIPE_FENCE_N(0); else PIPE_FENCE_N(2);
    f32x16 sa, sb;
    #pragma unroll
    for(int r=0;r<16;r++){ sa[r]=0.f; sb[r]=0.f; }
    #pragma unroll
    for(int q=0;q<4;q++){
      bf16x8 Qh4 = *(const bf16x8*)&stg[bi][q*64 + l];
      bf16x8 Ql4 = *(const bf16x8*)&stg[bi][256 + q*64 + l];
      sa = MFMA32(Qh4, Kh[q],  sa);
      sb = MFMA32(Ql4, Kh[q],  sb);
      sb = MFMA32(Qh4, Kl4[q], sb);
    }
    float p = 0.f;
    #pragma unroll
    for(int r=0;r<16;r++) p += __expf(sa[r]+sb[r]);
    zacc += p;
    if(it+2<8) ZISSUE(jq*8+it+2, (it+2)%3);
  }
#undef ZISSUE
  zacc += __shfl_down(zacc, 32);
  if(l<32) Zp[((size_t)(jq*8 + b))*Nn + mt*32 + l] = zacc;
}

// ===== fused: Pp[mo][b,j,c]; 4 m-quarters; E'=exp(S+lniz); 3-buffer pipeline; 4 blocks/CU =====
__global__ __launch_bounds__(256,4) void fused_k(
    const unsigned short* __restrict__ Qhi, const unsigned short* __restrict__ Qlo,
    const unsigned short* __restrict__ Khi, const unsigned short* __restrict__ Klo,
    const unsigned short* __restrict__ xf, const float* __restrict__ Zp,
    float* __restrict__ Pp){
  __shared__ uint4 stg[3][768];  // 36 KB
  __shared__ float lniz[512];
  int id = blockIdx.x;
  int b = id&7; int jb = (id>>3)&15; int mo = id>>7;   // 8 x 16 x 4 = 512 blocks
  int t = threadIdx.x, w = t>>6, l = t&63, lr = l&31, hh = l>>5;
  int js = jb*4 + w;
  #pragma unroll
  for(int i=0;i<2;i++){
    int m = mo*512 + i*256 + t;
    float z = 0.f;
    #pragma unroll
    for(int p=0;p<8;p++) z += Zp[((size_t)(p*8 + b))*Nn + m];
    lniz[i*256+t] = -__logf(z);
  }
  bf16x8 Qh4[4], Ql4[4];
  #pragma unroll
  for(int q=0;q<4;q++){
    Qh4[q] = *(const bf16x8*)(Qhi + qk_chunk(b, js, q, l));
    Ql4[q] = *(const bf16x8*)(Qlo + qk_chunk(b, js, q, l));
  }
  __syncthreads();   // lniz visible to all waves
#define FISSUE(S, BI) { \
    char* wb = (char*)&stg[BI][0] + ((t>>6)<<10); \
    load_lds16(Khi + qk_chunk(b,(S),0,0) + t*8, wb); \
    load_lds16(Klo + qk_chunk(b,(S),0,0) + t*8, wb + 4096); \
    load_lds16(xf + xz_chunk(b,2*(S),0,0) + t*8, wb + 8192); }
  FISSUE(mo*16,   0);
  FISSUE(mo*16+1, 1);
  f32x16 pa0, pa1;
  #pragma unroll
  for(int r=0;r<16;r++){ pa0[r]=0.f; pa1[r]=0.f; }
  #pragma unroll
  for(int it=0; it<16; it++){
    const int bi = it%3;
    if(it==15) PIPE_FENCE_N(0); else PIPE_FENCE_N(3);
    f32x16 sa, sb;
    #pragma unroll
    for(int r=0;r<16;r++){ sa[r]=0.f; sb[r]=0.f; }
    #pragma unroll
    for(int q=0;q<4;q++){
      bf16x8 Kh4 = *(const bf16x8*)&stg[bi][q*64 + l];
      bf16x8 Kl4 = *(const bf16x8*)&stg[bi][256 + q*64 + l];
      sa = MFMA32(Kh4, Qh4[q], sa);
      sb = MFMA32(Kl4, Qh4[q], sb);
      sb = MFMA32(Kh4, Ql4[q], sb);
    }
    bf16x8 b00 = *(const bf16x8*)&stg[bi][512 + l];
    bf16x8 b10 = *(const bf16x8*)&stg[bi][512 + 64 + l];
    bf16x8 b01 = *(const bf16x8*)&stg[bi][512 + 128 + l];
    bf16x8 b11 = *(const bf16x8*)&stg[bi][512 + 192 + l];
    float e[16];
    #pragma unroll
    for(int r=0;r<16;r++){
      int mrow = (r&3) + 8*(r>>2) + 4*hh;
      e[r] = __expf(sa[r] + sb[r] + lniz[it*32 + mrow]);
    }
    unsigned wd0,wd1,wd2,wd3,wd4,wd5,wd6,wd7;
    {
      unsigned x0 = pk2(e[0],  e[1]);
      unsigned x1 = pk2(e[2],  e[3]);
      unsigned y0 = pk2(e[4],  e[5]);
      unsigned y1 = pk2(e[6],  e[7]);
      asm("v_permlane32_swap_b32 %0, %1" : "+v"(x0), "+v"(y0));
      asm("v_permlane32_swap_b32 %0, %1" : "+v"(x1), "+v"(y1));
      wd0=x0; wd1=x1; wd2=y0; wd3=y1;
      unsigned x2 = pk2(e[8],  e[9]);
      unsigned x3 = pk2(e[10], e[11]);
      unsigned y2 = pk2(e[12], e[13]);
      unsigned y3 = pk2(e[14], e[15]);
      asm("v_permlane32_swap_b32 %0, %1" : "+v"(x2), "+v"(y2));
      asm("v_permlane32_swap_b32 %0, %1" : "+v"(x3), "+v"(y3));
      wd4=x2; wd5=x3; wd6=y2; wd7=y3;
    }
    u32x4 u1 = {wd0,wd1,wd2,wd3};
    u32x4 u2 = {wd4,wd5,wd6,wd7};
    bf16x8 f1 = __builtin_bit_cast(bf16x8, u1);
    bf16x8 f2 = __builtin_bit_cast(bf16x8, u2);
    pa0 = MFMA32(f1, b00, pa0);
    pa0 = MFMA32(f2, b01, pa0);
    pa1 = MFMA32(f1, b10, pa1);
    pa1 = MFMA32(f2, b11, pa1);
    if(it+2<16) FISSUE(mo*16+it+2, (it+2)%3);
  }
#undef FISSUE
  float* Pb = Pp + ((size_t)(mo*8 + b)*Nn + js*32)*Cc;
  #pragma unroll
  for(int r=0;r<16;r++){
    int jr = (r&3) + 8*(r>>2) + 4*hh;
    Pb[(size_t)jr*Cc + lr]      = pa0[r];
    Pb[(size_t)jr*Cc + 32 + lr] = pa1[r];
  }
}

// ===== psum: P = sum of 4 m-quarter partials (streaming, coalesced) =====
__global__ __launch_bounds__(256) void psum_k(const float* __restrict__ Pp,
                                              float* __restrict__ P){
  size_t i = ((size_t)blockIdx.x*256 + threadIdx.x)*4;
  const size_t st = (size_t)Bb*Nn*Cc;
  f32x4 a = *(const f32x4*)(Pp + i);
  f32x4 b = *(const f32x4*)(Pp + st + i);
  f32x4 c = *(const f32x4*)(Pp + 2*st + i);
  f32x4 d = *(const f32x4*)(Pp + 3*st + i);
  *(f32x4*)(P + i) = (a+b)+(c+d);
}

// ---------------- final: dy_diag + elementwise combine (single P gather) ----------------
__global__ __launch_bounds__(256) void final_k(const float* __restrict__ x,
    const float* __restrict__ xt, const float* __restrict__ P,
    const float* __restrict__ WvT, const float* __restrict__ Xp,
    const float* __restrict__ r_, const float* __restrict__ diagA,
    const int* __restrict__ cnt, const int* __restrict__ idx,
    const float* __restrict__ val, const float* __restrict__ tb,
    const float* __restrict__ alp, const float* __restrict__ bet,
    float* __restrict__ out){
  int t=threadIdx.x; int l=t&63;
  int bn = blockIdx.x*4 + (t>>6);
  int b = bn>>11, n = bn&2047;
  float wv = WvT[n*Cc+l];
  float xs = 0.f;
  const float* xpb = Xp + (size_t)b*32*Cc;
  #pragma unroll 8
  for(int p=0;p<32;p++) xs += xpb[p*Cc + l];
  float tacc = r_[n]*xs;
  int cn = cnt[n];
  const float* Pb = P + (size_t)b*Nn*Cc;
  const int* ix = idx + n*CAPS;
  const float* vl = val + n*CAPS;
  for(int k=0;k<cn;k++)
    tacc += vl[k] * Pb[(size_t)ix[k]*Cc + l];
  float d = wv*tacc;
  #pragma unroll
  for(int off=32;off>=1;off>>=1) d += __shfl_xor(d,off);
  size_t g = (size_t)bn*Cc + l;
  float o = alp[0]*diagA[n]*x[g] + bet[0]*(d*xt[g] + tb[l]);
  out[g] = fmaxf(o,0.f);
}

extern "C" void kernel_launch(void* const* d_in, const int* in_sizes, int n_in,
                              void* d_out, int out_size, void* d_ws, size_t ws_size,
                              hipStream_t stream){
  const float* x  = (const float*)d_in[0];
  const float* A  = (const float*)d_in[1];
  const float* Wq = (const float*)d_in[2];
  const float* Wk = (const float*)d_in[3];
  const float* Wv = (const float*)d_in[4];
  const float* Tw = (const float*)d_in[5];
  const float* tb = (const float*)d_in[6];
  const float* alp= (const float*)d_in[7];
  const float* bet= (const float*)d_in[8];
  float* out = (float*)d_out;

  char* base = (char*)d_ws; size_t off=0;
  auto al=[&](size_t sz)->void*{ void* q = base+off; off=(off+sz+255)&~(size_t)255; return q; };
  unsigned short* Qhi=(unsigned short*)al((size_t)Bb*Nn*Cc*2);
  unsigned short* Qlo=(unsigned short*)al((size_t)Bb*Nn*Cc*2);
  unsigned short* Khi=(unsigned short*)al((size_t)Bb*Nn*Cc*2);
  unsigned short* Klo=(unsigned short*)al((size_t)Bb*Nn*Cc*2);
  float* xt  =(float*)al((size_t)Bb*Nn*Cc*4);
  float* Pp  =(float*)al((size_t)4*Bb*Nn*Cc*4);
  float* P   =(float*)al((size_t)Bb*Nn*Cc*4);
  float* Zp  =(float*)al((size_t)8*Bb*Nn*4);
  float* Xp  =(float*)al((size_t)256*Cc*4);
  float* WvT =(float*)al((size_t)Nn*Cc*4);
  float* r_  =(float*)al((size_t)Nn*4);
  float* dgA =(float*)al((size_t)Nn*4);
  int*   cnt =(int*)al((size_t)Nn*4);
  int*   idx =(int*)al((size_t)Nn*CAPS*4);
  float* val =(float*)al((size_t)Nn*CAPS*4);
  unsigned short* xf=(unsigned short*)al((size_t)Bb*Cc*Nn*2);
  (void)ws_size; (void)n_in; (void)in_sizes; (void)out_size;

  mega_k<<<800, 256, 0, stream>>>(x, A, Wq, Wk, Tw, Wv,
      Qhi, Qlo, Khi, Klo, xt, Xp, r_, dgA, cnt, idx, val, WvT, xf);
  zpass_k<<<1024, 256, 0, stream>>>(Qhi,Qlo,Khi,Klo,Zp);
  fused_k<<<512, 256, 0, stream>>>(Qhi,Qlo,Khi,Klo,xf,Zp,Pp);
  psum_k<<<(int)((size_t)Bb*Nn*Cc/4/256), 256, 0, stream>>>(Pp,P);
  final_k<<<Bb*Nn/4, 256, 0, stream>>>(x,xt,P,WvT,Xp,r_,dgA,cnt,idx,val,tb,alp,bet,out);
}